// Round 5
// baseline (272.748 us; speedup 1.0000x reference)
//
#include <hip/hip_runtime.h>

// Focal loss (gamma=2, w0=w1=1) mean over N=2^25: -mean(log(s)*(1-s)^2),
// s = t ? p : 1-p. Two-stage reduction (no atomics).
//
// R4 post-mortem: GSIZE/grid tweaks neutral -> not the lever. R3 confounded
// two changes (pipelining + nontemporal). R2 counters showed L3 serving HALF
// the footprint (FETCH_SIZE = 134 MB of 268 MB) -- inputs are L3-resident
// after the harness restore. nt loads bypass that fast path. R5: identical
// structure to R4, but PLAIN loads (single-variable experiment: nt removed).

typedef float v4f __attribute__((ext_vector_type(4)));
typedef int   v4i __attribute__((ext_vector_type(4)));

constexpr int   N_TOTAL = 33554432;
constexpr int   N_VEC   = N_TOTAL / 4;        // 8388608 float4
constexpr int   THREADS = 256;
constexpr int   BLOCKS  = 4096;
constexpr int   VPB     = N_VEC / BLOCKS;     // 2048 vec4 per block
constexpr int   PAIRS   = VPB / THREADS;      // 8 vec4-pairs per thread
constexpr int   GSIZE   = 2;                  // pairs per pipeline group
constexpr int   GROUPS  = PAIRS / GSIZE;      // 4 groups
constexpr float NEG_INV_N = -1.0f / 33554432.0f;

__device__ __forceinline__ float term4(v4f p, v4i t) {
    float r = 0.0f;
#pragma unroll
    for (int j = 0; j < 4; ++j) {
        float s = (t[j] == 1) ? p[j] : (1.0f - p[j]);
        float q = 1.0f - s;
        r += __logf(s) * q * q;
    }
    return r;
}

__global__ __launch_bounds__(THREADS) void focal_partial_kernel(
    const v4f* __restrict__ inp,
    const v4i* __restrict__ tgt,
    float* __restrict__ partials)
{
    const int base = blockIdx.x * VPB + threadIdx.x;

    v4f pbuf[2][GSIZE];
    v4i tbuf[2][GSIZE];

    // prologue: group 0's loads in flight (plain loads -- L3 can serve)
#pragma unroll
    for (int k = 0; k < GSIZE; ++k) {
        int idx = base + k * THREADS;
        pbuf[0][k] = inp[idx];
        tbuf[0][k] = tgt[idx];
    }

    float acc = 0.0f;
#pragma unroll
    for (int g = 0; g < GROUPS; ++g) {
        const int cur = g & 1, nxt = cur ^ 1;
        // prefetch group g+1 before consuming group g
        if (g + 1 < GROUPS) {
#pragma unroll
            for (int k = 0; k < GSIZE; ++k) {
                int idx = base + ((g + 1) * GSIZE + k) * THREADS;
                pbuf[nxt][k] = inp[idx];
                tbuf[nxt][k] = tgt[idx];
            }
        }
#pragma unroll
        for (int k = 0; k < GSIZE; ++k)
            acc += term4(pbuf[cur][k], tbuf[cur][k]);
    }

    // wave-64 shuffle reduction
#pragma unroll
    for (int off = 32; off > 0; off >>= 1)
        acc += __shfl_down(acc, off, 64);

    __shared__ float ws[THREADS / 64];
    int lane = threadIdx.x & 63;
    int wave = threadIdx.x >> 6;
    if (lane == 0) ws[wave] = acc;
    __syncthreads();

    if (threadIdx.x == 0)
        partials[blockIdx.x] = ws[0] + ws[1] + ws[2] + ws[3];
}

__global__ __launch_bounds__(THREADS) void focal_final_kernel(
    const float* __restrict__ partials,
    float* __restrict__ out)
{
    float acc = 0.0f;
#pragma unroll
    for (int k = 0; k < BLOCKS / THREADS; ++k)
        acc += partials[k * THREADS + threadIdx.x];

#pragma unroll
    for (int off = 32; off > 0; off >>= 1)
        acc += __shfl_down(acc, off, 64);

    __shared__ float ws[THREADS / 64];
    int lane = threadIdx.x & 63;
    int wave = threadIdx.x >> 6;
    if (lane == 0) ws[wave] = acc;
    __syncthreads();

    if (threadIdx.x == 0)
        out[0] = (ws[0] + ws[1] + ws[2] + ws[3]) * NEG_INV_N;
}

extern "C" void kernel_launch(void* const* d_in, const int* in_sizes, int n_in,
                              void* d_out, int out_size, void* d_ws, size_t ws_size,
                              hipStream_t stream) {
    const v4f* inp = (const v4f*)d_in[0];
    const v4i* tgt = (const v4i*)d_in[1];
    float*     out = (float*)d_out;
    float*     partials = (float*)d_ws;   // 16 KB scratch (4096 floats)

    focal_partial_kernel<<<BLOCKS, THREADS, 0, stream>>>(inp, tgt, partials);
    focal_final_kernel<<<1, THREADS, 0, stream>>>(partials, out);
}

// Round 6
// 261.276 us; speedup vs baseline: 1.0439x; 1.0439x over previous
//
#include <hip/hip_runtime.h>

// Focal loss (gamma=2, w0=w1=1) mean over N=2^25: -mean(log(s)*(1-s)^2),
// s = t ? p : 1-p. Two-stage reduction (no atomics).
//
// R5 post-mortem (single-variable): nt loads = 75 us kernel, plain = 99.5 us.
// Plain-load counters: FETCH_SIZE = exactly ONE stream (128 MiB), 1.35 TB/s.
// Model: harness restores inp then tgt -> tgt is L3-resident, inp is not.
// Plain inp thrashes L2 (allocate on 134 MB stream, 4 MiB/XCD) -> 1.35 TB/s;
// nt-everything forces BOTH streams from HBM (bypasses tgt's L3 hit).
// R6: MIXED -- inp nontemporal (HBM stream, no cache pollution),
//              tgt plain (served from L3, zero HBM bytes).

typedef float v4f __attribute__((ext_vector_type(4)));
typedef int   v4i __attribute__((ext_vector_type(4)));

constexpr int   N_TOTAL = 33554432;
constexpr int   N_VEC   = N_TOTAL / 4;        // 8388608 float4
constexpr int   THREADS = 256;
constexpr int   BLOCKS  = 4096;
constexpr int   VPB     = N_VEC / BLOCKS;     // 2048 vec4 per block
constexpr int   PAIRS   = VPB / THREADS;      // 8 vec4-pairs per thread
constexpr int   GSIZE   = 2;                  // pairs per pipeline group
constexpr int   GROUPS  = PAIRS / GSIZE;      // 4 groups
constexpr float NEG_INV_N = -1.0f / 33554432.0f;

__device__ __forceinline__ float term4(v4f p, v4i t) {
    float r = 0.0f;
#pragma unroll
    for (int j = 0; j < 4; ++j) {
        float s = (t[j] == 1) ? p[j] : (1.0f - p[j]);
        float q = 1.0f - s;
        r += __logf(s) * q * q;
    }
    return r;
}

__global__ __launch_bounds__(THREADS) void focal_partial_kernel(
    const v4f* __restrict__ inp,
    const v4i* __restrict__ tgt,
    float* __restrict__ partials)
{
    const int base = blockIdx.x * VPB + threadIdx.x;

    v4f pbuf[2][GSIZE];
    v4i tbuf[2][GSIZE];

    // prologue: inp = nontemporal (HBM stream, don't allocate in L2/L3),
    //           tgt = plain (L3-resident after harness restore).
#pragma unroll
    for (int k = 0; k < GSIZE; ++k) {
        int idx = base + k * THREADS;
        pbuf[0][k] = __builtin_nontemporal_load(&inp[idx]);
        tbuf[0][k] = tgt[idx];
    }

    float acc = 0.0f;
#pragma unroll
    for (int g = 0; g < GROUPS; ++g) {
        const int cur = g & 1, nxt = cur ^ 1;
        // prefetch group g+1 before consuming group g
        if (g + 1 < GROUPS) {
#pragma unroll
            for (int k = 0; k < GSIZE; ++k) {
                int idx = base + ((g + 1) * GSIZE + k) * THREADS;
                pbuf[nxt][k] = __builtin_nontemporal_load(&inp[idx]);
                tbuf[nxt][k] = tgt[idx];
            }
        }
#pragma unroll
        for (int k = 0; k < GSIZE; ++k)
            acc += term4(pbuf[cur][k], tbuf[cur][k]);
    }

    // wave-64 shuffle reduction
#pragma unroll
    for (int off = 32; off > 0; off >>= 1)
        acc += __shfl_down(acc, off, 64);

    __shared__ float ws[THREADS / 64];
    int lane = threadIdx.x & 63;
    int wave = threadIdx.x >> 6;
    if (lane == 0) ws[wave] = acc;
    __syncthreads();

    if (threadIdx.x == 0)
        partials[blockIdx.x] = ws[0] + ws[1] + ws[2] + ws[3];
}

__global__ __launch_bounds__(THREADS) void focal_final_kernel(
    const float* __restrict__ partials,
    float* __restrict__ out)
{
    float acc = 0.0f;
#pragma unroll
    for (int k = 0; k < BLOCKS / THREADS; ++k)
        acc += partials[k * THREADS + threadIdx.x];

#pragma unroll
    for (int off = 32; off > 0; off >>= 1)
        acc += __shfl_down(acc, off, 64);

    __shared__ float ws[THREADS / 64];
    int lane = threadIdx.x & 63;
    int wave = threadIdx.x >> 6;
    if (lane == 0) ws[wave] = acc;
    __syncthreads();

    if (threadIdx.x == 0)
        out[0] = (ws[0] + ws[1] + ws[2] + ws[3]) * NEG_INV_N;
}

extern "C" void kernel_launch(void* const* d_in, const int* in_sizes, int n_in,
                              void* d_out, int out_size, void* d_ws, size_t ws_size,
                              hipStream_t stream) {
    const v4f* inp = (const v4f*)d_in[0];
    const v4i* tgt = (const v4i*)d_in[1];
    float*     out = (float*)d_out;
    float*     partials = (float*)d_ws;   // 16 KB scratch (4096 floats)

    focal_partial_kernel<<<BLOCKS, THREADS, 0, stream>>>(inp, tgt, partials);
    focal_final_kernel<<<1, THREADS, 0, stream>>>(partials, out);
}

// Round 7
// 247.715 us; speedup vs baseline: 1.1011x; 1.0547x over previous
//
#include <hip/hip_runtime.h>

// Focal loss (gamma=2, w0=w1=1) mean over N=2^25: -mean(log(s)*(1-s)^2),
// s = t ? p : 1-p. Two-stage reduction (no atomics).
//
// R6 post-mortem: mixed nt/plain regressed (kernel ~88 us vs ~74 all-nt).
// Timed-regime model: harness's 512 MiB ws-poison + 256 MiB restore leave
// caches cold/dirty at kernel time; ANY plain stream pays L2/L3
// allocate-thrash; all-nt is optimal. The kernel's window shares DRAM with
// ~256 MiB of harness writeback flushes: 256 MiB reads + 256 MiB flush in
// ~75 us = 6.8 TB/s = measured DRAM ceiling -> kernel is at the roofline.
// R7: revert to best-measured config (R3: all-nt, GSIZE=4, 2048 blocks).

typedef float v4f __attribute__((ext_vector_type(4)));
typedef int   v4i __attribute__((ext_vector_type(4)));

constexpr int   N_TOTAL = 33554432;
constexpr int   N_VEC   = N_TOTAL / 4;        // 8388608 float4
constexpr int   THREADS = 256;
constexpr int   BLOCKS  = 2048;
constexpr int   VPB     = N_VEC / BLOCKS;     // 4096 vec4 per block
constexpr int   PAIRS   = VPB / THREADS;      // 16 vec4-pairs per thread
constexpr int   GSIZE   = 4;                  // pairs per pipeline group
constexpr int   GROUPS  = PAIRS / GSIZE;      // 4 groups
constexpr float NEG_INV_N = -1.0f / 33554432.0f;

__device__ __forceinline__ float term4(v4f p, v4i t) {
    float r = 0.0f;
#pragma unroll
    for (int j = 0; j < 4; ++j) {
        float s = (t[j] == 1) ? p[j] : (1.0f - p[j]);
        float q = 1.0f - s;
        r += __logf(s) * q * q;
    }
    return r;
}

__global__ __launch_bounds__(THREADS) void focal_partial_kernel(
    const v4f* __restrict__ inp,
    const v4i* __restrict__ tgt,
    float* __restrict__ partials)
{
    const int base = blockIdx.x * VPB + threadIdx.x;

    v4f pbuf[2][GSIZE];
    v4i tbuf[2][GSIZE];

    // prologue: group 0's 8 loads in flight (nt: cold read-once streams,
    // bypass cache allocation -> no L2/L3 thrash)
#pragma unroll
    for (int k = 0; k < GSIZE; ++k) {
        int idx = base + k * THREADS;
        pbuf[0][k] = __builtin_nontemporal_load(&inp[idx]);
        tbuf[0][k] = __builtin_nontemporal_load(&tgt[idx]);
    }

    float acc = 0.0f;
#pragma unroll
    for (int g = 0; g < GROUPS; ++g) {
        const int cur = g & 1, nxt = cur ^ 1;
        // prefetch group g+1 before consuming group g
        if (g + 1 < GROUPS) {
#pragma unroll
            for (int k = 0; k < GSIZE; ++k) {
                int idx = base + ((g + 1) * GSIZE + k) * THREADS;
                pbuf[nxt][k] = __builtin_nontemporal_load(&inp[idx]);
                tbuf[nxt][k] = __builtin_nontemporal_load(&tgt[idx]);
            }
        }
#pragma unroll
        for (int k = 0; k < GSIZE; ++k)
            acc += term4(pbuf[cur][k], tbuf[cur][k]);
    }

    // wave-64 shuffle reduction
#pragma unroll
    for (int off = 32; off > 0; off >>= 1)
        acc += __shfl_down(acc, off, 64);

    __shared__ float ws[THREADS / 64];
    int lane = threadIdx.x & 63;
    int wave = threadIdx.x >> 6;
    if (lane == 0) ws[wave] = acc;
    __syncthreads();

    if (threadIdx.x == 0)
        partials[blockIdx.x] = ws[0] + ws[1] + ws[2] + ws[3];
}

__global__ __launch_bounds__(THREADS) void focal_final_kernel(
    const float* __restrict__ partials,
    float* __restrict__ out)
{
    float acc = 0.0f;
#pragma unroll
    for (int k = 0; k < BLOCKS / THREADS; ++k)
        acc += partials[k * THREADS + threadIdx.x];

#pragma unroll
    for (int off = 32; off > 0; off >>= 1)
        acc += __shfl_down(acc, off, 64);

    __shared__ float ws[THREADS / 64];
    int lane = threadIdx.x & 63;
    int wave = threadIdx.x >> 6;
    if (lane == 0) ws[wave] = acc;
    __syncthreads();

    if (threadIdx.x == 0)
        out[0] = (ws[0] + ws[1] + ws[2] + ws[3]) * NEG_INV_N;
}

extern "C" void kernel_launch(void* const* d_in, const int* in_sizes, int n_in,
                              void* d_out, int out_size, void* d_ws, size_t ws_size,
                              hipStream_t stream) {
    const v4f* inp = (const v4f*)d_in[0];
    const v4i* tgt = (const v4i*)d_in[1];
    float*     out = (float*)d_out;
    float*     partials = (float*)d_ws;   // 8 KB scratch (2048 floats)

    focal_partial_kernel<<<BLOCKS, THREADS, 0, stream>>>(inp, tgt, partials);
    focal_final_kernel<<<1, THREADS, 0, stream>>>(partials, out);
}